// Round 3
// baseline (1116.311 us; speedup 1.0000x reference)
//
#include <hip/hip_runtime.h>
#include <stdint.h>

typedef __bf16 bf16x8 __attribute__((ext_vector_type(8)));
typedef float f32x4 __attribute__((ext_vector_type(4)));
typedef unsigned short u16x8 __attribute__((ext_vector_type(8)));

// float -> bf16 bits, round-to-nearest-even (finite inputs)
__device__ __forceinline__ unsigned short f2bf(float f) {
    unsigned int u = __builtin_bit_cast(unsigned int, f);
    unsigned int r = u + 0x7fffu + ((u >> 16) & 1u);
    return (unsigned short)(r >> 16);
}

// Load 8 consecutive elements (element-index idx) as bf16 bits; converts from
// fp32 when isf32. All call sites are 16B-aligned in both interpretations.
__device__ __forceinline__ u16x8 load8(const void* p, size_t idx, bool isf32) {
    if (!isf32) return *reinterpret_cast<const u16x8*>((const unsigned short*)p + idx);
    const float* f = (const float*)p + idx;
    f32x4 a = *reinterpret_cast<const f32x4*>(f);
    f32x4 b = *reinterpret_cast<const f32x4*>(f + 4);
    u16x8 r;
    r[0] = f2bf(a[0]); r[1] = f2bf(a[1]); r[2] = f2bf(a[2]); r[3] = f2bf(a[3]);
    r[4] = f2bf(b[0]); r[5] = f2bf(b[1]); r[6] = f2bf(b[2]); r[7] = f2bf(b[3]);
    return r;
}

// ---------------------------------------------------------------------------
// Mixed-dtype GEMM via bf16 MFMA: C[M,N] = A[M,K] @ B[K,N], fp32 accumulate.
// Per-operand dtype flags: aF32/bF32 select fp32->bf16 conversion at stage
// time; cF32 selects fp32 vs bf16 output. Tile 64x64, BK=32, 4 waves.
// mfma_f32_16x16x32_bf16 maps (verified m89/m91/m120):
//   A-frag[j] = A[m=lane&15][k=(lane>>4)*8+j]
//   B-frag[j] = B[k=(lane>>4)*8+j][n=lane&15]
//   D[r]      = C[row=(lane>>4)*4+r][col=lane&15]
// ---------------------------------------------------------------------------
__global__ __launch_bounds__(256) void gemm_bf16(
    const void* __restrict__ A,
    const void* __restrict__ Bm,
    void* __restrict__ C,
    int M, int N, int K,
    int aF32, int bF32, int cF32)
{
    __shared__ unsigned short As[64][40];   // [m][k], row 80B: 2-way banks (free)
    __shared__ unsigned short Bt[64][40];   // [n][k], B staged transposed

    const int tid  = threadIdx.x;
    const int w    = tid >> 6;
    const int lane = tid & 63;
    const int quad = lane >> 4;
    const int l16  = lane & 15;
    const int m0   = blockIdx.y * 64;
    const int n0   = blockIdx.x * 64;

    f32x4 acc[4] = {};

    const int arow = tid >> 2;          // 0..63
    const int acol = (tid & 3) * 8;     // 0,8,16,24
    const int brow = tid >> 3;          // k 0..31
    const int bcol = (tid & 7) * 8;     // n 0..56

    const size_t aBase = (size_t)(m0 + arow) * K + acol;
    const size_t bBase = (size_t)brow * N + (n0 + bcol);

    for (int k0 = 0; k0 < K; k0 += 32) {
        u16x8 av = load8(A,  aBase + k0, aF32 != 0);
        u16x8 bv = load8(Bm, bBase + (size_t)k0 * N, bF32 != 0);
        *reinterpret_cast<u16x8*>(&As[arow][acol]) = av;
        #pragma unroll
        for (int j = 0; j < 8; j++) Bt[bcol + j][brow] = bv[j];
        __syncthreads();

        bf16x8 af = *reinterpret_cast<const bf16x8*>(&As[16 * w + l16][quad * 8]);
        #pragma unroll
        for (int c = 0; c < 4; c++) {
            bf16x8 bf = *reinterpret_cast<const bf16x8*>(&Bt[16 * c + l16][quad * 8]);
            acc[c] = __builtin_amdgcn_mfma_f32_16x16x32_bf16(af, bf, acc[c], 0, 0, 0);
        }
        __syncthreads();
    }

    #pragma unroll
    for (int c = 0; c < 4; c++) {
        #pragma unroll
        for (int r = 0; r < 4; r++) {
            const int row = m0 + 16 * w + quad * 4 + r;
            const int col = n0 + 16 * c + l16;
            const size_t off = (size_t)row * N + col;
            if (cF32) ((float*)C)[off] = acc[c][r];
            else ((unsigned short*)C)[off] = f2bf(acc[c][r]);
        }
    }
}

// ---------------------------------------------------------------------------
// Causal flash attention over packed qkv [B,T,3C] (bf16 workspace).
// Grid: (T/64, B*H). Block: 256 = 4 waves; wave w owns q-rows [q0+16w,+16)
// with private online-softmax state. KV tiles of 32.
// ---------------------------------------------------------------------------
__global__ __launch_bounds__(256) void flash_attn(
    const unsigned short* __restrict__ qkv,
    unsigned short* __restrict__ Out)
{
    const int T = 2048, CH = 6144, HD = 128, CO = 2048;

    __shared__ unsigned short Ks[32][136];   // [kv][d], row 272B = 17x16B
    __shared__ unsigned short Vt[128][40];   // [d][kv], transposed for PV B-frags
    __shared__ unsigned short Ps[4][16][40]; // per-wave P roundtrip (C/D -> A layout)

    const int tid  = threadIdx.x;
    const int w    = tid >> 6;
    const int lane = tid & 63;
    const int quad = lane >> 4;
    const int l16  = lane & 15;
    const int bh   = blockIdx.y;
    const int b    = bh >> 4;
    const int h    = bh & 15;
    const int q0   = blockIdx.x * 64;

    const size_t base = (size_t)b * T * CH + (size_t)h * HD;
    const unsigned short* Qp = qkv + base;
    const unsigned short* Kp = qkv + base + 2048;
    const unsigned short* Vp = qkv + base + 4096;

    bf16x8 qf[4];
    {
        const unsigned short* qrow = Qp + (size_t)(q0 + 16 * w + l16) * CH;
        #pragma unroll
        for (int dc = 0; dc < 4; dc++)
            qf[dc] = *reinterpret_cast<const bf16x8*>(qrow + dc * 32 + quad * 8);
    }

    f32x4 o[8] = {};
    float m_i[4], l_i[4];
    #pragma unroll
    for (int r = 0; r < 4; r++) { m_i[r] = -__builtin_inff(); l_i[r] = 0.f; }

    const int qrow_out = q0 + 16 * w + quad * 4;   // + r
    const int itMax = (q0 + 64) / 32;              // block-uniform causal bound
    const float sc = 0.08838834764831845f * 1.4426950408889634f; // D^-0.5 * log2(e)

    const int kvr = tid >> 3;         // 0..31
    const int dc0 = (tid & 7) * 16;   // 0..112

    for (int it = 0; it < itMax; it++) {
        const int kv0 = it * 32;
        const unsigned short* krow = Kp + (size_t)(kv0 + kvr) * CH + dc0;
        const unsigned short* vrow = Vp + (size_t)(kv0 + kvr) * CH + dc0;
        u16x8 k0v = *reinterpret_cast<const u16x8*>(krow);
        u16x8 k1v = *reinterpret_cast<const u16x8*>(krow + 8);
        u16x8 v0v = *reinterpret_cast<const u16x8*>(vrow);
        u16x8 v1v = *reinterpret_cast<const u16x8*>(vrow + 8);
        *reinterpret_cast<u16x8*>(&Ks[kvr][dc0])     = k0v;
        *reinterpret_cast<u16x8*>(&Ks[kvr][dc0 + 8]) = k1v;
        #pragma unroll
        for (int j = 0; j < 8; j++) {
            Vt[dc0 + j][kvr]     = v0v[j];
            Vt[dc0 + 8 + j][kvr] = v1v[j];
        }
        __syncthreads();

        // S = Q K^T (16 x 32)
        f32x4 s[2];
        #pragma unroll
        for (int nt = 0; nt < 2; nt++) {
            s[nt] = (f32x4){0.f, 0.f, 0.f, 0.f};
            #pragma unroll
            for (int dc = 0; dc < 4; dc++) {
                bf16x8 bf = *reinterpret_cast<const bf16x8*>(&Ks[16 * nt + l16][dc * 32 + quad * 8]);
                s[nt] = __builtin_amdgcn_mfma_f32_16x16x32_bf16(qf[dc], bf, s[nt], 0, 0, 0);
            }
        }

        // scale, causal mask, online softmax (16-lane row groups)
        #pragma unroll
        for (int r = 0; r < 4; r++) {
            const int qi = qrow_out + r;
            #pragma unroll
            for (int nt = 0; nt < 2; nt++) {
                const int ki = kv0 + nt * 16 + l16;
                float v = s[nt][r] * sc;
                s[nt][r] = (ki <= qi) ? v : -__builtin_inff();
            }
            float v = fmaxf(s[0][r], s[1][r]);
            v = fmaxf(v, __shfl_xor(v, 1));
            v = fmaxf(v, __shfl_xor(v, 2));
            v = fmaxf(v, __shfl_xor(v, 4));
            v = fmaxf(v, __shfl_xor(v, 8));
            const float mnew  = fmaxf(m_i[r], v);      // finite after tile 0
            const float alpha = exp2f(m_i[r] - mnew);
            float p0 = exp2f(s[0][r] - mnew);
            float p1 = exp2f(s[1][r] - mnew);
            float ps = p0 + p1;
            ps += __shfl_xor(ps, 1);
            ps += __shfl_xor(ps, 2);
            ps += __shfl_xor(ps, 4);
            ps += __shfl_xor(ps, 8);
            l_i[r] = l_i[r] * alpha + ps;
            m_i[r] = mnew;
            #pragma unroll
            for (int c = 0; c < 8; c++) o[c][r] *= alpha;
            Ps[w][quad * 4 + r][l16]      = f2bf(p0);
            Ps[w][quad * 4 + r][16 + l16] = f2bf(p1);
        }
        __syncthreads();

        // O += P V
        bf16x8 pf = *reinterpret_cast<const bf16x8*>(&Ps[w][l16][quad * 8]);
        #pragma unroll
        for (int c = 0; c < 8; c++) {
            bf16x8 vf = *reinterpret_cast<const bf16x8*>(&Vt[c * 16 + l16][quad * 8]);
            o[c] = __builtin_amdgcn_mfma_f32_16x16x32_bf16(pf, vf, o[c], 0, 0, 0);
        }
        __syncthreads();
    }

    #pragma unroll
    for (int r = 0; r < 4; r++) {
        const float inv = 1.0f / l_i[r];
        const size_t row = (size_t)(b * T + qrow_out + r) * CO + h * HD;
        #pragma unroll
        for (int c = 0; c < 8; c++)
            Out[row + c * 16 + l16] = f2bf(o[c][r] * inv);
    }
}

extern "C" void kernel_launch(void* const* d_in, const int* in_sizes, int n_in,
                              void* d_out, int out_size, void* d_ws, size_t ws_size,
                              hipStream_t stream) {
    const int B = 2, T = 2048, C = 2048;
    const void* x    = d_in[0];   // fp32 [B,T,C]
    // d_in[1] = causal mask, statically known -> ignored
    const void* Wqkv = d_in[2];   // fp32 [C,3C]
    const void* Wout = d_in[3];   // fp32 [C,C]

    unsigned short* qkv = (unsigned short*)d_ws;          // [B*T,3C] bf16 = 50.3 MB
    unsigned short* O   = qkv + (size_t)B * T * 3 * C;    // [B*T,C]  bf16 = 16.8 MB

    const int M = B * T;          // 4096

    // 1) qkv = x @ Wqkv   [4096x2048]@[2048x6144]  A:fp32 B:fp32 -> C:bf16 ws
    gemm_bf16<<<dim3(3 * C / 64, M / 64), 256, 0, stream>>>(x, Wqkv, qkv, M, 3 * C, C, 1, 1, 0);
    // 2) flash attention (causal) over bf16 qkv -> bf16 O
    flash_attn<<<dim3(T / 64, B * 16), 256, 0, stream>>>(qkv, O);
    // 3) out = O @ Wout   [4096x2048]@[2048x2048]  A:bf16 ws B:fp32 -> C:fp32 out
    gemm_bf16<<<dim3(C / 64, M / 64), 256, 0, stream>>>(O, Wout, d_out, M, C, C, 0, 1, 1);
}

// Round 4
// 526.031 us; speedup vs baseline: 2.1221x; 2.1221x over previous
//
#include <hip/hip_runtime.h>
#include <stdint.h>

typedef __bf16 bf16x8 __attribute__((ext_vector_type(8)));
typedef float f32x4 __attribute__((ext_vector_type(4)));
typedef unsigned short u16x8 __attribute__((ext_vector_type(8)));

__device__ __forceinline__ unsigned short f2bf(float f) {
    unsigned int u = __builtin_bit_cast(unsigned int, f);
    unsigned int r = u + 0x7fffu + ((u >> 16) & 1u);
    return (unsigned short)(r >> 16);
}

// async global->LDS, 16B per lane. LDS dest = wave-uniform base + lane*16.
__device__ __forceinline__ void async16(const void* g, void* l) {
    __builtin_amdgcn_global_load_lds(
        (const __attribute__((address_space(1))) void*)g,
        (__attribute__((address_space(3))) void*)l, 16, 0, 0);
}

// ---------------------------------------------------------------------------
// x fp32 -> bf16, elementwise (8 elems/thread)
// ---------------------------------------------------------------------------
__global__ __launch_bounds__(256) void cast_bf16(
    const float* __restrict__ src, unsigned short* __restrict__ dst, int n8)
{
    int i = blockIdx.x * 256 + threadIdx.x;
    if (i >= n8) return;
    const float* f = src + (size_t)i * 8;
    f32x4 a = *reinterpret_cast<const f32x4*>(f);
    f32x4 b = *reinterpret_cast<const f32x4*>(f + 4);
    u16x8 r;
    r[0]=f2bf(a[0]); r[1]=f2bf(a[1]); r[2]=f2bf(a[2]); r[3]=f2bf(a[3]);
    r[4]=f2bf(b[0]); r[5]=f2bf(b[1]); r[6]=f2bf(b[2]); r[7]=f2bf(b[3]);
    *reinterpret_cast<u16x8*>(dst + (size_t)i * 8) = r;
}

// ---------------------------------------------------------------------------
// W fp32 [R][Cc] -> bf16 W^T [Cc][R]. 64x64 tiles, XOR-swizzled LDS
// (element (r,c) at St[c*64 + ((r>>3 ^ ((c>>4)&3))<<3) + (r&7)]).
// ---------------------------------------------------------------------------
__global__ __launch_bounds__(256) void transpose_cast_f32(
    const float* __restrict__ src, unsigned short* __restrict__ dst, int R, int Cc)
{
    __shared__ unsigned short St[64 * 64];
    const int tid = threadIdx.x;
    const int r0 = blockIdx.y * 64, c0 = blockIdx.x * 64;
    const int lr  = tid >> 2;          // 0..63
    const int lcb = (tid & 3) * 16;    // 0,16,32,48
    const float* sp = src + (size_t)(r0 + lr) * Cc + c0 + lcb;
    #pragma unroll
    for (int u = 0; u < 4; u++) {
        f32x4 v = *reinterpret_cast<const f32x4*>(sp + 4 * u);
        #pragma unroll
        for (int e = 0; e < 4; e++) {
            int c = lcb + 4 * u + e;
            St[c * 64 + (((lr >> 3) ^ ((c >> 4) & 3)) << 3) + (lr & 7)] = f2bf(v[e]);
        }
    }
    __syncthreads();
    #pragma unroll
    for (int i = 0; i < 2; i++) {
        int ck = tid + 256 * i;
        int c = ck >> 3, ch = ck & 7;
        u16x8 val = *reinterpret_cast<const u16x8*>(&St[c * 64 + ((ch ^ ((c >> 4) & 3)) << 3)]);
        *reinterpret_cast<u16x8*>(dst + (size_t)(c0 + c) * R + r0 + ch * 8) = val;
    }
}

// ---------------------------------------------------------------------------
// V-part of qkv [b,t,4096+h*128+d] (bf16) -> VT [b][h][d][t] (bf16).
// Same swizzled-tile transpose, 64x64 per block; grid (T/64, 2, B*H).
// ---------------------------------------------------------------------------
__global__ __launch_bounds__(256) void vtrans(
    const unsigned short* __restrict__ qkv, unsigned short* __restrict__ VT)
{
    const int T = 2048, CH = 6144;
    __shared__ unsigned short St[64 * 64];
    const int tid = threadIdx.x;
    const int bh = blockIdx.z, b = bh >> 4, h = bh & 15;
    const int t0 = blockIdx.x * 64, d0 = blockIdx.y * 64;
    const int lr  = tid >> 2;
    const int lcb = (tid & 3) * 16;
    const unsigned short* sp = qkv + (size_t)(b * T + t0 + lr) * CH + 4096 + h * 128 + d0 + lcb;
    u16x8 v0 = *reinterpret_cast<const u16x8*>(sp);
    u16x8 v1 = *reinterpret_cast<const u16x8*>(sp + 8);
    #pragma unroll
    for (int e = 0; e < 8; e++) {
        int c = lcb + e;
        St[c * 64 + (((lr >> 3) ^ ((c >> 4) & 3)) << 3) + (lr & 7)] = v0[e];
        c = lcb + 8 + e;
        St[c * 64 + (((lr >> 3) ^ ((c >> 4) & 3)) << 3) + (lr & 7)] = v1[e];
    }
    __syncthreads();
    #pragma unroll
    for (int i = 0; i < 2; i++) {
        int ck = tid + 256 * i;
        int d = ck >> 3, ch = ck & 7;
        u16x8 val = *reinterpret_cast<const u16x8*>(&St[d * 64 + ((ch ^ ((d >> 4) & 3)) << 3)]);
        *reinterpret_cast<u16x8*>(VT + ((size_t)bh * 128 + d0 + d) * T + t0 + ch * 8) = val;
    }
}

// ---------------------------------------------------------------------------
// m97-style GEMM: C[M,N] = A[M,K] @ BT[N,K]^T, bf16 in, fp32 acc.
// 128x128 tile, BK=32, 4 waves (2x2 of 64x64), global_load_lds width-16.
// ---------------------------------------------------------------------------
__global__ __launch_bounds__(256) void gemm_bt(
    const unsigned short* __restrict__ A,   // [M][K] bf16
    const unsigned short* __restrict__ BT,  // [N][K] bf16
    void* __restrict__ C, int M, int N, int K, int cF32)
{
    __shared__ unsigned short As[128 * 32];
    __shared__ unsigned short Bs[128 * 32];
    const int tid = threadIdx.x;
    const int w = tid >> 6, lane = tid & 63;
    const int quad = lane >> 4, l16 = lane & 15;
    const int wm = (w >> 1) * 64, wn = (w & 1) * 64;
    const int m0 = blockIdx.y * 128, n0 = blockIdx.x * 128;

    const int srow = w * 16 + (lane >> 2);     // staging row (inst 0)
    const int scol = (lane & 3) * 8;
    const unsigned short* aG = A  + (size_t)(m0 + srow) * K + scol;
    const unsigned short* bG = BT + (size_t)(n0 + srow) * K + scol;
    unsigned short* aL = As + (w * 16) * 32;   // wave-uniform LDS bases
    unsigned short* bL = Bs + (w * 16) * 32;

    f32x4 acc[4][4] = {};

    for (int k0 = 0; k0 < K; k0 += 32) {
        async16(aG + k0, aL);
        async16(aG + (size_t)64 * K + k0, aL + 64 * 32);
        async16(bG + k0, bL);
        async16(bG + (size_t)64 * K + k0, bL + 64 * 32);
        __syncthreads();

        bf16x8 af[4], bf[4];
        #pragma unroll
        for (int i = 0; i < 4; i++)
            af[i] = *reinterpret_cast<const bf16x8*>(&As[(wm + i * 16 + l16) * 32 + quad * 8]);
        #pragma unroll
        for (int c = 0; c < 4; c++)
            bf[c] = *reinterpret_cast<const bf16x8*>(&Bs[(wn + c * 16 + l16) * 32 + quad * 8]);
        #pragma unroll
        for (int i = 0; i < 4; i++)
            #pragma unroll
            for (int c = 0; c < 4; c++)
                acc[i][c] = __builtin_amdgcn_mfma_f32_16x16x32_bf16(af[i], bf[c], acc[i][c], 0, 0, 0);
        __syncthreads();
    }

    #pragma unroll
    for (int i = 0; i < 4; i++)
        #pragma unroll
        for (int c = 0; c < 4; c++)
            #pragma unroll
            for (int r = 0; r < 4; r++) {
                const int row = m0 + wm + i * 16 + quad * 4 + r;
                const int col = n0 + wn + c * 16 + l16;
                const size_t off = (size_t)row * N + col;
                if (cF32) ((float*)C)[off] = acc[i][c][r];
                else ((unsigned short*)C)[off] = f2bf(acc[i][c][r]);
            }
}

// ---------------------------------------------------------------------------
// Flash attention v2 (causal). Q-tile 128 (4 waves x 2 strips of 16 rows),
// KV-tile 64. K and V^T staged via global_load_lds with XOR chunk-swizzle
// (swizzle applied to the global fetch index; LDS stays lane-contiguous).
// ---------------------------------------------------------------------------
__global__ __launch_bounds__(256, 2) void flash_attn(
    const unsigned short* __restrict__ qkv,
    const unsigned short* __restrict__ VT,
    unsigned short* __restrict__ Out)
{
    const int T = 2048, CH = 6144;
    __shared__ unsigned short Ks[64 * 128];   // [kv][d-chunk swizzled]
    __shared__ unsigned short Vt[128 * 64];   // [d][kv-chunk swizzled]
    __shared__ unsigned short Ps[4 * 32 * 72];// per-wave P, pitch 72

    const int tid = threadIdx.x;
    const int w = tid >> 6, lane = tid & 63;
    const int quad = lane >> 4, l16 = lane & 15;
    const int bh = blockIdx.y, b = bh >> 4, h = bh & 15;
    const int q0 = (gridDim.x - 1 - blockIdx.x) * 128;   // heavy blocks first

    // Q fragments: strip st rows q0+w*32+st*16+l16, k = dc*32+quad*8..
    bf16x8 qf[2][4];
    #pragma unroll
    for (int st = 0; st < 2; st++) {
        const unsigned short* qrow = qkv + (size_t)(b * T + q0 + w * 32 + st * 16 + l16) * CH + h * 128;
        #pragma unroll
        for (int dc = 0; dc < 4; dc++)
            qf[st][dc] = *reinterpret_cast<const bf16x8*>(qrow + dc * 32 + quad * 8);
    }

    f32x4 o[2][8] = {};
    float m_i[2][4], l_i[2][4];
    #pragma unroll
    for (int st = 0; st < 2; st++)
        #pragma unroll
        for (int r = 0; r < 4; r++) { m_i[st][r] = -__builtin_inff(); l_i[st][r] = 0.f; }

    const float sc = 0.08838834764831845f * 1.4426950408889634f;
    const int xsw = l16 & 7;   // read-side swizzle key
    unsigned short* PsW = Ps + w * 32 * 72;

    for (int kv0 = 0; kv0 < q0 + 128; kv0 += 64) {
        // ---- stage K tile (64 rows x 128 d) ----
        #pragma unroll
        for (int i = 0; i < 4; i++) {
            const int r0 = i * 16 + w * 4;
            const int kv = r0 + (lane >> 4);
            const int ch = (lane & 15) ^ (kv & 7);
            async16(qkv + (size_t)(b * T + kv0 + kv) * CH + 2048 + h * 128 + ch * 8,
                    Ks + r0 * 128);
        }
        // ---- stage V^T tile (128 d-rows x 64 kv) ----
        #pragma unroll
        for (int i = 0; i < 4; i++) {
            const int r0 = i * 32 + w * 8;
            const int d = r0 + (lane >> 3);
            const int ch = (lane & 7) ^ (d & 7);
            async16(VT + ((size_t)bh * 128 + d) * T + kv0 + ch * 8,
                    Vt + r0 * 64);
        }
        __syncthreads();

        // ---- S = Q K^T: 2 strips x (16 x 64) ----
        f32x4 s[2][4] = {};
        #pragma unroll
        for (int dc = 0; dc < 4; dc++)
            #pragma unroll
            for (int nt = 0; nt < 4; nt++) {
                bf16x8 kf = *reinterpret_cast<const bf16x8*>(
                    &Ks[(nt * 16 + l16) * 128 + ((((dc * 4 + quad)) ^ xsw) << 3)]);
                s[0][nt] = __builtin_amdgcn_mfma_f32_16x16x32_bf16(qf[0][dc], kf, s[0][nt], 0, 0, 0);
                s[1][nt] = __builtin_amdgcn_mfma_f32_16x16x32_bf16(qf[1][dc], kf, s[1][nt], 0, 0, 0);
            }

        // ---- online softmax per strip ----
        #pragma unroll
        for (int st = 0; st < 2; st++) {
            const int qb = q0 + w * 32 + st * 16 + quad * 4;
            #pragma unroll
            for (int r = 0; r < 4; r++) {
                const int qi = qb + r;
                float mx = -__builtin_inff();
                #pragma unroll
                for (int nt = 0; nt < 4; nt++) {
                    float v = s[st][nt][r] * sc;
                    v = (kv0 + nt * 16 + l16 <= qi) ? v : -__builtin_inff();
                    s[st][nt][r] = v;
                    mx = fmaxf(mx, v);
                }
                mx = fmaxf(mx, __shfl_xor(mx, 1));
                mx = fmaxf(mx, __shfl_xor(mx, 2));
                mx = fmaxf(mx, __shfl_xor(mx, 4));
                mx = fmaxf(mx, __shfl_xor(mx, 8));
                const float mnew  = fmaxf(m_i[st][r], mx);   // finite (kv0<=qi always)
                const float alpha = exp2f(m_i[st][r] - mnew);
                m_i[st][r] = mnew;
                float ps = 0.f;
                #pragma unroll
                for (int nt = 0; nt < 4; nt++) {
                    float p = exp2f(s[st][nt][r] - mnew);
                    ps += p;
                    PsW[(st * 16 + quad * 4 + r) * 72 + nt * 16 + l16] = f2bf(p);
                }
                ps += __shfl_xor(ps, 1);
                ps += __shfl_xor(ps, 2);
                ps += __shfl_xor(ps, 4);
                ps += __shfl_xor(ps, 8);
                l_i[st][r] = l_i[st][r] * alpha + ps;
                #pragma unroll
                for (int c = 0; c < 8; c++) o[st][c][r] *= alpha;
            }
        }

        // ---- O += P V (Ps is per-wave; compiler inserts lgkm waits) ----
        #pragma unroll
        for (int kc = 0; kc < 2; kc++) {
            bf16x8 pf0 = *reinterpret_cast<const bf16x8*>(&PsW[l16 * 72 + kc * 32 + quad * 8]);
            bf16x8 pf1 = *reinterpret_cast<const bf16x8*>(&PsW[(16 + l16) * 72 + kc * 32 + quad * 8]);
            #pragma unroll
            for (int c = 0; c < 8; c++) {
                bf16x8 vf = *reinterpret_cast<const bf16x8*>(
                    &Vt[(c * 16 + l16) * 64 + (((kc * 4 + quad) ^ xsw) << 3)]);
                o[0][c] = __builtin_amdgcn_mfma_f32_16x16x32_bf16(pf0, vf, o[0][c], 0, 0, 0);
                o[1][c] = __builtin_amdgcn_mfma_f32_16x16x32_bf16(pf1, vf, o[1][c], 0, 0, 0);
            }
        }
        __syncthreads();
    }

    #pragma unroll
    for (int st = 0; st < 2; st++)
        #pragma unroll
        for (int r = 0; r < 4; r++) {
            const float inv = 1.0f / l_i[st][r];
            const int row = q0 + w * 32 + st * 16 + quad * 4 + r;
            const size_t base = (size_t)(b * T + row) * 2048 + h * 128;
            #pragma unroll
            for (int c = 0; c < 8; c++)
                Out[base + c * 16 + l16] = f2bf(o[st][c][r] * inv);
        }
}

extern "C" void kernel_launch(void* const* d_in, const int* in_sizes, int n_in,
                              void* d_out, int out_size, void* d_ws, size_t ws_size,
                              hipStream_t stream) {
    const int B = 2, T = 2048, C = 2048;
    const float* x    = (const float*)d_in[0];
    const float* Wqkv = (const float*)d_in[2];   // [C][3C] fp32
    const float* Wout = (const float*)d_in[3];   // [C][C]  fp32
    const int M = B * T;                         // 4096

    // workspace layout (regions reused across phases):
    //   qkv  : 50.33 MB (bf16 [M][3C])
    //   A    : 16.78 MB (xb during GEMM1; WoutT after)
    //   Bb   : 25.17 MB (WqkvT during GEMM1; VT after)
    //   O    : 16.78 MB
    char* ws = (char*)d_ws;
    unsigned short* qkv   = (unsigned short*)ws;                       // +0
    unsigned short* xb    = (unsigned short*)(ws + 50331648);          // region A
    unsigned short* WoutT = xb;
    unsigned short* WqkvT = (unsigned short*)(ws + 67108864);          // region B
    unsigned short* VTp   = WqkvT;
    unsigned short* O     = (unsigned short*)(ws + 92274688);

    // 1) casts for GEMM1
    cast_bf16<<<dim3(M * C / 8 / 256), 256, 0, stream>>>(x, xb, M * C / 8);
    transpose_cast_f32<<<dim3(3 * C / 64, C / 64), 256, 0, stream>>>(Wqkv, WqkvT, C, 3 * C);
    // 2) qkv = xb @ WqkvT^T
    gemm_bt<<<dim3(3 * C / 128, M / 128), 256, 0, stream>>>(xb, WqkvT, qkv, M, 3 * C, C, 0);
    // 3) V transpose (region B now free) and Wout cast (region A now free)
    vtrans<<<dim3(T / 64, 2, B * 16), 256, 0, stream>>>(qkv, VTp);
    transpose_cast_f32<<<dim3(C / 64, C / 64), 256, 0, stream>>>(Wout, WoutT, C, C);
    // 4) flash attention
    flash_attn<<<dim3(T / 128, B * 16), 256, 0, stream>>>(qkv, VTp, O);
    // 5) out = O @ WoutT^T (fp32 out)
    gemm_bt<<<dim3(C / 128, M / 128), 256, 0, stream>>>(O, WoutT, d_out, M, C, C, 1);
}